// Round 1
// 197.918 us; speedup vs baseline: 1.0299x; 1.0299x over previous
//
#include <hip/hip_runtime.h>

#define NB 32
#define NT 512
#define ND 384
#define DUR_MAX 8
#define MAX_OUT (NT * (DUR_MAX - 1))   // 3584
#define NV (ND / 4)                    // 96 float4 per row
#define NWG ((NB * MAX_OUT * NV) / 256)  // 43008 gather blocks (divisible by 8)

// Kernel 1: per-batch inclusive scan (shfl wave-scan, 2 barriers) + scatter of
// precomputed source base addresses; tail filled with -1 sentinels so the
// gather needs neither a totals[] load nor a separate valid check.
__global__ __launch_bounds__(NT) void lr_scan_scatter(
    const int* __restrict__ dur, int* __restrict__ idxmap)
{
    __shared__ int wsum[NT / 64];
    const int b    = blockIdx.x;
    const int t    = threadIdx.x;
    const int lane = t & 63;
    const int w    = t >> 6;

    int d = dur[b * NT + t];
    d = d > 0 ? d : 0;            // patched = max(round(1.0*d), 0) == max(d,0)

    // wave-level inclusive scan (64 lanes, 6 shfl steps, no barriers)
    int v = d;
    #pragma unroll
    for (int off = 1; off < 64; off <<= 1) {
        int u = __shfl_up(v, off);
        if (lane >= off) v += u;
    }
    if (lane == 63) wsum[w] = v;
    __syncthreads();
    if (t == 0) {
        int acc = 0;
        #pragma unroll
        for (int i = 0; i < NT / 64; ++i) { acc += wsum[i]; wsum[i] = acc; }
    }
    __syncthreads();
    const int cum   = v + (w ? wsum[w - 1] : 0);
    const int total = wsum[NT / 64 - 1];
    const int start = cum - d;

    int* base = idxmap + b * MAX_OUT;
    const int src = (b * NT + t) * NV;          // precomputed float4 base of row t
    for (int j = 0; j < d; ++j) base[start + j] = src;
    // zero-fill sentinel for invalid tail positions [total, MAX_OUT)
    for (int s = total + t; s < MAX_OUT; s += NT) base[s] = -1;
}

// Kernel 2: one thread per output float4, XCD-swizzled so each XCD's blocks
// cover exactly 4 batches (3 MB input + 57 KB idxmap -> L2-resident).
__global__ __launch_bounds__(256) void lr_gather(
    const float4* __restrict__ in, const int* __restrict__ idxmap,
    float4* __restrict__ out)
{
    const unsigned bid = blockIdx.x;
    const unsigned per = NWG / 8;                       // 5376 blocks per XCD
    const unsigned swz = (bid & 7u) * per + (bid >> 3); // bijective (NWG % 8 == 0)
    const unsigned g   = swz * 256u + threadIdx.x;
    const unsigned row = g / NV;           // (b, pos) flattened
    const unsigned col = g - row * NV;

    const int src = idxmap[row];
    float4 r = make_float4(0.f, 0.f, 0.f, 0.f);
    if (src >= 0) r = in[src + col];
    out[g] = r;
}

extern "C" void kernel_launch(void* const* d_in, const int* in_sizes, int n_in,
                              void* d_out, int out_size, void* d_ws, size_t ws_size,
                              hipStream_t stream)
{
    const float* x   = (const float*)d_in[0];
    const int*   dur = (const int*)d_in[1];
    float* out = (float*)d_out;

    int* idxmap = (int*)d_ws;                  // NB*MAX_OUT ints

    lr_scan_scatter<<<NB, NT, 0, stream>>>(dur, idxmap);
    lr_gather<<<NWG, 256, 0, stream>>>((const float4*)x, idxmap, (float4*)out);
}